// Round 10
// baseline (3176.363 us; speedup 1.0000x reference)
//
#include <hip/hip_runtime.h>
#include <stdint.h>

#define NN 2048
#define DD 512
#define NWORDS 8

typedef unsigned int u32;
typedef unsigned char u8;

__device__ __forceinline__ float sigmoidf_(float x){ return 1.0f/(1.0f+expf(-x)); }

// ---------------- build adjacency bitmask ----------------
__global__ void k_zero_bm(u32* bm, u32* dead0){
  int t = blockIdx.x*256+threadIdx.x;
  if(t<NN*NWORDS) bm[t]=0u;
  else if(t<NN*NWORDS+64) dead0[t-NN*NWORDS]=0u;
}

__global__ void k_scatter(const int* __restrict__ ei, u32* __restrict__ bm){
  int t = blockIdx.x*256+threadIdx.x;
  if(t>=32768) return;
  int r = ei[t];
  int c = ei[32768+t];
  atomicOr(&bm[r*NWORDS + ((c>>5)&7)], 1u<<(c&31));
}

// bm2[r] = OR over neighbors of bm[k]; deg; transposed bitmask bmT[w][2048]; dead0 bits
__global__ void k_bm2_deg(const u32* __restrict__ bm, u32* __restrict__ bm2, int* __restrict__ deg,
                          u32* __restrict__ bmT, u32* __restrict__ dead0){
  int r = blockIdx.x*256+threadIdx.x;
  if(r>=NN) return;
  int base = r & ~255;
  u32 acc[NWORDS];
  #pragma unroll
  for(int w=0;w<NWORDS;++w) acc[w]=0u;
  int d=0;
  #pragma unroll
  for(int w=0;w<NWORDS;++w){
    u32 m = bm[r*NWORDS+w];
    bmT[(w<<11)+r] = m;
    d += __popc(m);
    int b0 = w<<5;
    while(m){ int j=__ffs((int)m)-1; m&=m-1;
      const u32* row = bm + (size_t)(base+b0+j)*NWORDS;
      #pragma unroll
      for(int w2=0;w2<NWORDS;++w2) acc[w2] |= row[w2];
    }
  }
  #pragma unroll
  for(int w=0;w<NWORDS;++w) bm2[r*NWORDS+w]=acc[w];
  deg[r]=d;
  if(d==0) atomicOr(&dead0[r>>5], 1u<<(r&31));
}

// ---------------- Vn ----------------
__global__ void k_vn(const float* __restrict__ x, const u32* __restrict__ bm,
                     const int* __restrict__ deg, float* __restrict__ Vn){
  int node = blockIdx.x*4 + (threadIdx.x>>6);
  int lane = threadIdx.x & 63;
  int base = node & ~255;
  float degf = (float)deg[node];
  float ax[8], axx[8];
  #pragma unroll
  for(int k=0;k<8;++k){ ax[k]=0.0f; axx[k]=0.0f; }
  #pragma unroll
  for(int w=0;w<NWORDS;++w){
    u32 m = bm[node*NWORDS+w]; int b0=w<<5;
    while(m){ int j=__ffs((int)m)-1; m&=m-1;
      const float* xr = x + (size_t)(base+b0+j)*DD;
      #pragma unroll
      for(int k=0;k<8;++k){ float v = xr[lane+64*k]; ax[k]+=v; axx[k]=fmaf(v,v,axx[k]); }
    }
  }
  const float* xi = x + (size_t)node*DD;
  double vn2 = 0.0;
  #pragma unroll
  for(int k=0;k<8;++k){
    float xf = xi[lane+64*k];
    float val = xf*(degf*xf - ax[k]) - xf*ax[k] + axx[k];
    vn2 += (double)val*(double)val;
  }
  #pragma unroll
  for(int off=32;off>0;off>>=1) vn2 += __shfl_down(vn2, off);
  if(lane==0) Vn[node] = (float)sqrt(vn2);
}

// ---------------- per-graph softmax entropy ----------------
__global__ void k_softent(const float* __restrict__ Vn, float* __restrict__ ent){
  __shared__ float red[4];
  __shared__ float sh;
  int g = blockIdx.x, tid = threadIdx.x;
  float v = Vn[g*256+tid];
  float m = v;
  #pragma unroll
  for(int off=32;off>0;off>>=1) m = fmaxf(m, __shfl_down(m,off));
  if((tid&63)==0) red[tid>>6]=m;
  __syncthreads();
  if(tid==0) sh = fmaxf(fmaxf(red[0],red[1]),fmaxf(red[2],red[3]));
  __syncthreads();
  float mx = sh;
  float e = expf(v-mx);
  float s = e;
  #pragma unroll
  for(int off=32;off>0;off>>=1) s += __shfl_down(s,off);
  if((tid&63)==0) red[tid>>6]=s;
  __syncthreads();
  if(tid==0) sh = red[0]+red[1]+red[2]+red[3];
  __syncthreads();
  float Pn = e / sh;
  if(Pn==0.0f) Pn=1.0f;
  ent[g*256+tid] = -Pn*logf(Pn);
}

// u = ent + A@ent
__global__ void k_u(const u32* __restrict__ bm, const float* __restrict__ ent, float* __restrict__ uo){
  int i = blockIdx.x*256+threadIdx.x;
  if(i>=NN) return;
  int base = i & ~255;
  float acc = ent[i];
  #pragma unroll
  for(int w=0;w<NWORDS;++w){
    u32 m = bm[i*NWORDS+w]; int b0=w<<5;
    while(m){ int j=__ffs((int)m)-1; m&=m-1; acc += ent[base+b0+j]; }
  }
  uo[i]=acc;
}

// h1 = relu(u * w11 + b11)
__global__ void k_h1(const float* __restrict__ u, const float* __restrict__ w11,
                     const float* __restrict__ b11, float* __restrict__ h){
  int t = blockIdx.x*256+threadIdx.x;
  if(t>=NN*DD) return;
  int i = t>>9; int f = t&511;
  h[t] = fmaxf(fmaf(u[i], w11[f], b11[f]), 0.0f);
}

// ---------------- tiled fp32 GEMM ----------------
template<int ACT>
__global__ __launch_bounds__(256) void k_gemm(const float* __restrict__ A, const float* __restrict__ B,
                                              const float* __restrict__ bias, float* __restrict__ C){
  __shared__ float As[32][68];
  __shared__ float Bs[32][68];
  int tid = threadIdx.x;
  int m0 = blockIdx.x*64;
  int n0 = blockIdx.y*64;
  int ty = tid>>4, tx = tid&15;
  float acc[4][4];
  #pragma unroll
  for(int i=0;i<4;++i){
    #pragma unroll
    for(int j=0;j<4;++j) acc[i][j]=0.0f;
  }
  for(int k0=0;k0<512;k0+=32){
    __syncthreads();
    #pragma unroll
    for(int t0=0;t0<2;++t0){
      int t = tid + t0*256;
      int row = t>>3, c4 = t&7;
      float4 v = *(const float4*)(A + (size_t)(m0+row)*512 + k0 + c4*4);
      As[c4*4+0][row]=v.x; As[c4*4+1][row]=v.y; As[c4*4+2][row]=v.z; As[c4*4+3][row]=v.w;
    }
    #pragma unroll
    for(int t0=0;t0<2;++t0){
      int t = tid + t0*256;
      int row = t>>4, c4 = t&15;
      float4 v = *(const float4*)(B + (size_t)(k0+row)*512 + n0 + c4*4);
      *(float4*)&Bs[row][c4*4] = v;
    }
    __syncthreads();
    #pragma unroll
    for(int kk=0;kk<32;++kk){
      float4 a = *(const float4*)&As[kk][ty*4];
      float4 b = *(const float4*)&Bs[kk][tx*4];
      float av[4]={a.x,a.y,a.z,a.w}, bv[4]={b.x,b.y,b.z,b.w};
      #pragma unroll
      for(int i=0;i<4;++i){
        #pragma unroll
        for(int j=0;j<4;++j) acc[i][j] = fmaf(av[i],bv[j],acc[i][j]);
      }
    }
  }
  #pragma unroll
  for(int i=0;i<4;++i){
    float4 o;
    float* oo = &o.x;
    #pragma unroll
    for(int j=0;j<4;++j){
      float v = acc[i][j] + bias[n0+tx*4+j];
      if(ACT==0) v = fmaxf(v,0.0f);
      else      v = 1.0f/(1.0f+expf(-v));
      oo[j]=v;
    }
    *(float4*)(C + (size_t)(m0+ty*4+i)*512 + n0 + tx*4) = o;
  }
}

// out = h + A@h
__global__ void k_spmm_add(const float* __restrict__ h, const u32* __restrict__ bm, float* __restrict__ out){
  int node = blockIdx.x*4 + (threadIdx.x>>6);
  int lane = threadIdx.x & 63;
  int base = node & ~255;
  float acc[8];
  #pragma unroll
  for(int k=0;k<8;++k) acc[k] = h[(size_t)node*DD + lane + 64*k];
  #pragma unroll
  for(int w=0;w<NWORDS;++w){
    u32 m = bm[node*NWORDS+w]; int b0=w<<5;
    while(m){ int j=__ffs((int)m)-1; m&=m-1;
      const float* hr = h + (size_t)(base+b0+j)*DD;
      #pragma unroll
      for(int k=0;k<8;++k) acc[k] += hr[lane+64*k];
    }
  }
  #pragma unroll
  for(int k=0;k<8;++k) out[(size_t)node*DD + lane + 64*k] = acc[k];
}

// prob = sigmoid(sigmoid(h@w33 + b33))
__global__ void k_gemv_prob(const float* __restrict__ h, const float* __restrict__ w33,
                            const float* __restrict__ b33, float* __restrict__ prob){
  int node = blockIdx.x*4 + (threadIdx.x>>6);
  int lane = threadIdx.x & 63;
  float acc = 0.0f;
  #pragma unroll
  for(int k=0;k<8;++k) acc = fmaf(h[(size_t)node*512 + lane + 64*k], w33[lane+64*k], acc);
  #pragma unroll
  for(int off=32;off>0;off>>=1) acc += __shfl_down(acc, off);
  if(lane==0){
    float z = sigmoidf_(acc + b33[0]);
    prob[node] = sigmoidf_(z);
  }
}

// ---------------- y = A@prob (fp64), per-graph c_g and gamma partials ----------------
__global__ __launch_bounds__(256) void k_y(const u32* __restrict__ bm, const float* __restrict__ prob,
                 const float* __restrict__ ent, double* __restrict__ y,
                 double* __restrict__ cg, double* __restrict__ gam){
  __shared__ float p_s[256];
  __shared__ double redc[4], redg[4];
  int g = blockIdx.x, i = threadIdx.x;
  int node = (g<<8) + i;
  float p = prob[node];
  p_s[i] = p;
  __syncthreads();
  double acc = 0.0;
  #pragma unroll
  for (int w = 0; w < NWORDS; ++w){
    u32 m = bm[(size_t)node*NWORDS + w];
    while (m){ int j=__ffs((int)m)-1; m&=m-1; acc += (double)p_s[(w<<5)+j]; }
  }
  y[node] = acc;
  double e = (double)ent[node];
  double c = (double)p*acc - e*(double)p;
  #pragma unroll
  for (int off=32; off>0; off>>=1){ c += __shfl_down(c,off); e += __shfl_down(e,off); }
  if ((i&63)==0){ redc[i>>6]=c; redg[i>>6]=e; }
  __syncthreads();
  if (i==0){ cg[g]=redc[0]+redc[1]+redc[2]+redc[3]; gam[g]=redg[0]+redg[1]+redg[2]+redg[3]; }
}

// ---------------- bitonic sort: order = argsort(-prob) stable ----------------
__global__ void k_sort(const float* __restrict__ prob, int* __restrict__ order){
  __shared__ float kp[NN];
  __shared__ int ki[NN];
  int tid = threadIdx.x; // 1024
  for(int t=tid;t<NN;t+=1024){ kp[t]=prob[t]; ki[t]=t; }
  __syncthreads();
  for(int k=2;k<=NN;k<<=1){
    for(int j=k>>1;j>0;j>>=1){
      for(int t=tid;t<NN;t+=1024){
        int l = t ^ j;
        if(l > t){
          bool up = ((t & k) == 0);
          float pa=kp[t]; int ia=ki[t]; float pb=kp[l]; int ib=ki[l];
          bool before_ab = (pa > pb) || (pa == pb && ia < ib);
          bool dosw = up ? (!before_ab) : before_ab;
          if(dosw){ kp[t]=pb; ki[t]=ib; kp[l]=pa; ki[l]=ia; }
        }
      }
      __syncthreads();
    }
  }
  for(int t=tid;t<NN;t+=1024) order[t]=ki[t];
}

// ---------------- single-wave incremental greedy scan ----------------
// Lane l owns columns {l, l+64, l+128, l+192} of the active graph.
// bmT layout: bmT_s[w*2048 + row] -> per-lane row reads are bank-conflict-free.
// Scattered dummy fetches are LDS reads (NOT shuffles: __shfl from an inactive
// source lane is undefined on CDNA, and these sites are divergent).
// Batch-ballot over the sorted order kills dead-skip cost.
__global__ void __launch_bounds__(64) k_scan(const u32* __restrict__ bmT, const u32* __restrict__ dead0,
    const float* __restrict__ ent, const float* __restrict__ prob, const int* __restrict__ order,
    const double* __restrict__ yg, const double* __restrict__ cgp, const double* __restrict__ gamp,
    float* __restrict__ selw, float* __restrict__ out_sel, float* __restrict__ out_loss)
{
  extern __shared__ char smem[];
  u32* bmT_s     = (u32*)smem;                    // 64 KB  [8][2048]
  double* y_s    = (double*)(smem + 65536);       // 16 KB
  float* dummy_s = (float*)(smem + 81920);        // 8 KB
  float* entf_s  = (float*)(smem + 90112);        // 8 KB
  int* order_s   = (int*)(smem + 98304);          // 8 KB
  u32* dead_s    = (u32*)(smem + 106496);         // 256 B
  u32* sel_s     = (u32*)(smem + 106752);         // 256 B
  int lane = threadIdx.x;

  for (int t=lane; t<4096; t+=64) ((uint4*)bmT_s)[t] = ((const uint4*)bmT)[t];
  for (int t=lane; t<NN; t+=64){
    dummy_s[t]=prob[t]; entf_s[t]=ent[t]; y_s[t]=yg[t]; order_s[t]=order[t];
  }
  { u32 d0=dead0[lane]; dead_s[lane]=d0; sel_s[lane]=d0; }
  double thr = 0.0;
  if (lane==0){
    double gg=0.0, cc=0.0;
    for(int i=0;i<8;++i){ gg+=gamp[i]; cc+=cgp[i]; }
    out_loss[0]=(float)(gg+cc);
  }
  __syncthreads();

  for (int pos=0; pos<NN; pos+=64){
    int myNode = order_s[pos+lane];
    int myW = myNode>>5, myB = myNode&31;
    int startLane = 0;
    while (true){
      bool aliveMe = (lane>=startLane) && !((dead_s[myW]>>myB)&1u);
      unsigned long long msk = __ballot(aliveMe);
      if (!msk) break;
      int k = (int)__builtin_ctzll(msk);
      int node = __shfl(myNode, k);        // wave-uniform shuffle (all lanes active)
      startLane = k+1;

      int base = node & ~255, r = node & 255, g = node>>8;
      u32 rv[8];
      #pragma unroll
      for(int w=0;w<8;++w) rv[w]=bmT_s[(w<<11)+node];  // broadcast
      float uv = 1.0f - dummy_s[node];                 // broadcast

      double part = 0.0;
      #pragma unroll
      for(int q=0;q<4;++q){
        int cl = lane + (q<<6);
        int c  = base + cl;
        bool isnb   = (rv[cl>>5]>>(cl&31))&1u;
        bool isself = (cl==r);
        if (isnb | isself){
          float  d  = dummy_s[c];
          double yv = y_s[c];
          float  e  = entf_s[c];
          float  u  = isself ? uv : -d;
          part += (double)u*(2.0*yv-(double)e);
          if (isnb){
            double ps=0.0;
            #pragma unroll
            for(int w=0;w<8;++w){
              u32 m = bmT_s[(w<<11)+c] & rv[w];        // conflict-free row read
              while(m){
                int j=__ffs((int)m)-1; m&=m-1;
                ps += (double)dummy_s[base+(w<<5)+j];  // scattered LDS gather (~1 hit)
              }
            }
            part += (double)d*ps - 2.0*(double)uv*(double)d;
          }
        }
      }
      #pragma unroll
      for(int off=1;off<64;off<<=1) part += __shfl_xor(part,off); // wave-uniform

      if (part <= thr){
        thr -= part;
        u32 supp[8];
        #pragma unroll
        for(int w=0;w<8;++w) supp[w]=rv[w];
        supp[r>>5] |= 1u<<(r&31);
        if (lane<8) dead_s[(g<<3)+lane] |= supp[lane]; // supp identical across lanes
        if (lane==0) sel_s[node>>5] |= 1u<<(node&31);
        // y update FIRST, reading OLD dummy values from LDS
        #pragma unroll
        for(int q=0;q<4;++q){
          int cl=lane+(q<<6); int c=base+cl;
          double dy=0.0;
          #pragma unroll
          for(int w=0;w<8;++w){
            u32 m = bmT_s[(w<<11)+c] & supp[w];
            while(m){
              int j=__ffs((int)m)-1; m&=m-1;
              int j2=(w<<5)+j;
              float ujf = (j2==r) ? uv : -dummy_s[base+j2];
              dy += (double)ujf;
            }
          }
          if (dy!=0.0) y_s[c]+=dy;
        }
        __syncthreads();   // all old-dummy reads complete before overwrite
        #pragma unroll
        for(int q=0;q<4;++q){
          int cl=lane+(q<<6); int c=base+cl;
          bool isnb = (rv[cl>>5]>>(cl&31))&1u;
          if (cl==r) dummy_s[c]=1.0f;
          else if (isnb) dummy_s[c]=0.0f;
        }
        __syncthreads();
      }
    }
  }

  for (int t=lane; t<NN; t+=64){
    float sv = ((sel_s[t>>5]>>(t&31))&1u)?1.0f:0.0f;
    selw[t]=sv; out_sel[t]=sv;
  }
}

// ---------------- outputs ----------------
__global__ void k_xpool(const float* __restrict__ x, const float* __restrict__ selw, float* __restrict__ out){
  int t = blockIdx.x*256+threadIdx.x;
  if(t >= NN*(DD/4)) return;
  int i = t >> 7;
  float s = selw[i];
  float4 v = ((const float4*)x)[t];
  v.x*=s; v.y*=s; v.z*=s; v.w*=s;
  ((float4*)out)[t] = v;
}

__global__ void k_adj(const u32* __restrict__ bm, const u32* __restrict__ bm2,
                      const float* __restrict__ selw, float* __restrict__ outadj){
  int r = blockIdx.x;
  int c = blockIdx.y*256 + threadIdx.x;
  float val = 0.0f;
  if ((r>>8)==(c>>8) && r!=c && selw[r]!=0.0f && selw[c]!=0.0f){
    int lc = c & 255;
    u32 any = (bm2[r*NWORDS + (lc>>5)] >> (lc&31)) & 1u;
    if(!any){
      #pragma unroll
      for(int w=0;w<NWORDS;++w) any |= (bm2[r*NWORDS+w] & bm[c*NWORDS+w]);
    }
    val = any ? 1.0f : 0.0f;
  }
  outadj[(size_t)r*2048 + c] = val;
}

extern "C" void kernel_launch(void* const* d_in, const int* in_sizes, int n_in,
                              void* d_out, int out_size, void* d_ws, size_t ws_size,
                              hipStream_t stream){
  const float* x  = (const float*)d_in[0];
  const int* ei   = (const int*)d_in[1];
  const float* w11=(const float*)d_in[3];  const float* b11=(const float*)d_in[4];
  const float* w12=(const float*)d_in[5];  const float* b12=(const float*)d_in[6];
  const float* w13=(const float*)d_in[7];  const float* b13=(const float*)d_in[8];
  const float* w21=(const float*)d_in[9];  const float* b21=(const float*)d_in[10];
  const float* w22=(const float*)d_in[11]; const float* b22=(const float*)d_in[12];
  const float* w23=(const float*)d_in[13]; const float* b23=(const float*)d_in[14];
  const float* w31=(const float*)d_in[15]; const float* b31=(const float*)d_in[16];
  const float* w32=(const float*)d_in[17]; const float* b32=(const float*)d_in[18];
  const float* w33=(const float*)d_in[19]; const float* b33=(const float*)d_in[20];

  char* ws = (char*)d_ws;
  u32* bm    = (u32*)(ws + 0);
  u32* bm2   = (u32*)(ws + 65536);
  int* deg   = (int*)(ws + 131072);
  float* Vn  = (float*)(ws + 139264);
  float* ent = (float*)(ws + 147456);
  float* uarr= (float*)(ws + 155648);
  float* prob= (float*)(ws + 163840);
  int* order = (int*)(ws + 172032);
  float* selw= (float*)(ws + 180224);
  double* yg = (double*)(ws + 196608);
  double* cg = (double*)(ws + 212992);
  double* gam= (double*)(ws + 213056);
  u32* bmT   = (u32*)(ws + 215040);   // 64 KB transposed bitmask
  u32* dead0 = (u32*)(ws + 313344);   // 256 B
  float* buf0= (float*)(ws + (1<<20));
  float* buf1= (float*)(ws + (1<<20) + (size_t)NN*DD*4);

  float* out = (float*)d_out;
  float* out_xp   = out;
  float* out_adj  = out + 1048576;
  float* out_sel  = out + 1048576 + 4194304;
  float* out_loss = out + 1048576 + 4194304 + 2048;

  hipFuncSetAttribute((const void*)k_scan, hipFuncAttributeMaxDynamicSharedMemorySize, 107008);

  k_zero_bm<<<65,256,0,stream>>>(bm, dead0);
  k_scatter<<<128,256,0,stream>>>(ei, bm);
  k_bm2_deg<<<8,256,0,stream>>>(bm, bm2, deg, bmT, dead0);
  k_vn<<<512,256,0,stream>>>(x, bm, deg, Vn);
  k_softent<<<8,256,0,stream>>>(Vn, ent);
  k_u<<<8,256,0,stream>>>(bm, ent, uarr);
  k_h1<<<4096,256,0,stream>>>(uarr, w11, b11, buf0);
  dim3 gg(32,8);
  k_gemm<0><<<gg,256,0,stream>>>(buf0, w12, b12, buf1);
  k_gemm<1><<<gg,256,0,stream>>>(buf1, w13, b13, buf0);
  k_spmm_add<<<512,256,0,stream>>>(buf0, bm, buf1);
  k_gemm<0><<<gg,256,0,stream>>>(buf1, w21, b21, buf0);
  k_gemm<0><<<gg,256,0,stream>>>(buf0, w22, b22, buf1);
  k_gemm<1><<<gg,256,0,stream>>>(buf1, w23, b23, buf0);
  k_spmm_add<<<512,256,0,stream>>>(buf0, bm, buf1);
  k_gemm<0><<<gg,256,0,stream>>>(buf1, w31, b31, buf0);
  k_gemm<0><<<gg,256,0,stream>>>(buf0, w32, b32, buf1);
  k_gemv_prob<<<512,256,0,stream>>>(buf1, w33, b33, prob);
  k_y<<<8,256,0,stream>>>(bm, prob, ent, yg, cg, gam);
  k_sort<<<1,1024,0,stream>>>(prob, order);
  k_scan<<<1,64,107008,stream>>>(bmT, dead0, ent, prob, order, yg, cg, gam, selw, out_sel, out_loss);
  k_xpool<<<1024,256,0,stream>>>(x, selw, out_xp);
  dim3 ga(2048,8);
  k_adj<<<ga,256,0,stream>>>(bm, bm2, selw, out_adj);
}

// Round 12
// 2705.392 us; speedup vs baseline: 1.1741x; 1.1741x over previous
//
#include <hip/hip_runtime.h>
#include <stdint.h>

#define NN 2048
#define DD 512
#define NWORDS 8
#define KPAIR 128

typedef unsigned int u32;
typedef unsigned short u16;
typedef unsigned char u8;
typedef unsigned long long ull;

__device__ __forceinline__ float sigmoidf_(float x){ return 1.0f/(1.0f+expf(-x)); }

// ---------------- build adjacency bitmask ----------------
__global__ void k_zero_bm(u32* bm, u32* dead0){
  int t = blockIdx.x*256+threadIdx.x;
  if(t<NN*NWORDS) bm[t]=0u;
  else if(t<NN*NWORDS+64) dead0[t-NN*NWORDS]=0u;
}

__global__ void k_scatter(const int* __restrict__ ei, u32* __restrict__ bm){
  int t = blockIdx.x*256+threadIdx.x;
  if(t>=32768) return;
  int r = ei[t];
  int c = ei[32768+t];
  atomicOr(&bm[r*NWORDS + ((c>>5)&7)], 1u<<(c&31));
}

// bm2; deg; bmT[w][2048]; dead0; pair lists (edges within nb(r), local cols, i<l)
__global__ void k_bm2_deg(const u32* __restrict__ bm, u32* __restrict__ bm2, int* __restrict__ deg,
                          u32* __restrict__ bmT, u32* __restrict__ dead0,
                          u16* __restrict__ pairT, u32* __restrict__ cntT){
  int r = blockIdx.x*256+threadIdx.x;
  if(r>=NN) return;
  int base = r & ~255;
  u32 rv[NWORDS], acc[NWORDS];
  #pragma unroll
  for(int w=0;w<NWORDS;++w){ rv[w]=bm[r*NWORDS+w]; bmT[(w<<11)+r]=rv[w]; acc[w]=0u; }
  int d=0, np=0;
  u16* prow = pairT + (size_t)r*KPAIR;
  #pragma unroll
  for(int w=0;w<NWORDS;++w){
    u32 m = rv[w];
    d += __popc(m);
    int b0 = w<<5;
    while(m){ int j=__ffs((int)m)-1; m&=m-1;
      int i = b0+j;
      const u32* row = bm + (size_t)(base+i)*NWORDS;
      #pragma unroll
      for(int w2=0;w2<NWORDS;++w2){
        u32 rw = row[w2];
        acc[w2] |= rw;
        u32 pm = rw & rv[w2];
        if (w2 < w) pm = 0u;
        else if (w2 == w) pm &= ~((2u<<j)-1u);   // only l > i
        while(pm){ int lb=__ffs((int)pm)-1; pm&=pm-1;
          int l = (w2<<5)+lb;
          if(np<KPAIR) prow[np] = (u16)((i<<8)|l);
          ++np;
        }
      }
    }
  }
  #pragma unroll
  for(int w=0;w<NWORDS;++w) bm2[r*NWORDS+w]=acc[w];
  deg[r]=d;
  cntT[r]=(u32)(np<KPAIR?np:KPAIR);
  if(d==0) atomicOr(&dead0[r>>5], 1u<<(r&31));
}

// ---------------- Vn ----------------
__global__ void k_vn(const float* __restrict__ x, const u32* __restrict__ bm,
                     const int* __restrict__ deg, float* __restrict__ Vn){
  int node = blockIdx.x*4 + (threadIdx.x>>6);
  int lane = threadIdx.x & 63;
  int base = node & ~255;
  float degf = (float)deg[node];
  float ax[8], axx[8];
  #pragma unroll
  for(int k=0;k<8;++k){ ax[k]=0.0f; axx[k]=0.0f; }
  #pragma unroll
  for(int w=0;w<NWORDS;++w){
    u32 m = bm[node*NWORDS+w]; int b0=w<<5;
    while(m){ int j=__ffs((int)m)-1; m&=m-1;
      const float* xr = x + (size_t)(base+b0+j)*DD;
      #pragma unroll
      for(int k=0;k<8;++k){ float v = xr[lane+64*k]; ax[k]+=v; axx[k]=fmaf(v,v,axx[k]); }
    }
  }
  const float* xi = x + (size_t)node*DD;
  double vn2 = 0.0;
  #pragma unroll
  for(int k=0;k<8;++k){
    float xf = xi[lane+64*k];
    float val = xf*(degf*xf - ax[k]) - xf*ax[k] + axx[k];
    vn2 += (double)val*(double)val;
  }
  #pragma unroll
  for(int off=32;off>0;off>>=1) vn2 += __shfl_down(vn2, off);
  if(lane==0) Vn[node] = (float)sqrt(vn2);
}

// ---------------- per-graph softmax entropy ----------------
__global__ void k_softent(const float* __restrict__ Vn, float* __restrict__ ent){
  __shared__ float red[4];
  __shared__ float sh;
  int g = blockIdx.x, tid = threadIdx.x;
  float v = Vn[g*256+tid];
  float m = v;
  #pragma unroll
  for(int off=32;off>0;off>>=1) m = fmaxf(m, __shfl_down(m,off));
  if((tid&63)==0) red[tid>>6]=m;
  __syncthreads();
  if(tid==0) sh = fmaxf(fmaxf(red[0],red[1]),fmaxf(red[2],red[3]));
  __syncthreads();
  float mx = sh;
  float e = expf(v-mx);
  float s = e;
  #pragma unroll
  for(int off=32;off>0;off>>=1) s += __shfl_down(s,off);
  if((tid&63)==0) red[tid>>6]=s;
  __syncthreads();
  if(tid==0) sh = red[0]+red[1]+red[2]+red[3];
  __syncthreads();
  float Pn = e / sh;
  if(Pn==0.0f) Pn=1.0f;
  ent[g*256+tid] = -Pn*logf(Pn);
}

// u = ent + A@ent
__global__ void k_u(const u32* __restrict__ bm, const float* __restrict__ ent, float* __restrict__ uo){
  int i = blockIdx.x*256+threadIdx.x;
  if(i>=NN) return;
  int base = i & ~255;
  float acc = ent[i];
  #pragma unroll
  for(int w=0;w<NWORDS;++w){
    u32 m = bm[i*NWORDS+w]; int b0=w<<5;
    while(m){ int j=__ffs((int)m)-1; m&=m-1; acc += ent[base+b0+j]; }
  }
  uo[i]=acc;
}

// h1 = relu(u * w11 + b11)
__global__ void k_h1(const float* __restrict__ u, const float* __restrict__ w11,
                     const float* __restrict__ b11, float* __restrict__ h){
  int t = blockIdx.x*256+threadIdx.x;
  if(t>=NN*DD) return;
  int i = t>>9; int f = t&511;
  h[t] = fmaxf(fmaf(u[i], w11[f], b11[f]), 0.0f);
}

// ---------------- tiled fp32 GEMM ----------------
template<int ACT>
__global__ __launch_bounds__(256) void k_gemm(const float* __restrict__ A, const float* __restrict__ B,
                                              const float* __restrict__ bias, float* __restrict__ C){
  __shared__ float As[32][68];
  __shared__ float Bs[32][68];
  int tid = threadIdx.x;
  int m0 = blockIdx.x*64;
  int n0 = blockIdx.y*64;
  int ty = tid>>4, tx = tid&15;
  float acc[4][4];
  #pragma unroll
  for(int i=0;i<4;++i){
    #pragma unroll
    for(int j=0;j<4;++j) acc[i][j]=0.0f;
  }
  for(int k0=0;k0<512;k0+=32){
    __syncthreads();
    #pragma unroll
    for(int t0=0;t0<2;++t0){
      int t = tid + t0*256;
      int row = t>>3, c4 = t&7;
      float4 v = *(const float4*)(A + (size_t)(m0+row)*512 + k0 + c4*4);
      As[c4*4+0][row]=v.x; As[c4*4+1][row]=v.y; As[c4*4+2][row]=v.z; As[c4*4+3][row]=v.w;
    }
    #pragma unroll
    for(int t0=0;t0<2;++t0){
      int t = tid + t0*256;
      int row = t>>4, c4 = t&15;
      float4 v = *(const float4*)(B + (size_t)(k0+row)*512 + n0 + c4*4);
      *(float4*)&Bs[row][c4*4] = v;
    }
    __syncthreads();
    #pragma unroll
    for(int kk=0;kk<32;++kk){
      float4 a = *(const float4*)&As[kk][ty*4];
      float4 b = *(const float4*)&Bs[kk][tx*4];
      float av[4]={a.x,a.y,a.z,a.w}, bv[4]={b.x,b.y,b.z,b.w};
      #pragma unroll
      for(int i=0;i<4;++i){
        #pragma unroll
        for(int j=0;j<4;++j) acc[i][j] = fmaf(av[i],bv[j],acc[i][j]);
      }
    }
  }
  #pragma unroll
  for(int i=0;i<4;++i){
    float4 o;
    float* oo = &o.x;
    #pragma unroll
    for(int j=0;j<4;++j){
      float v = acc[i][j] + bias[n0+tx*4+j];
      if(ACT==0) v = fmaxf(v,0.0f);
      else      v = 1.0f/(1.0f+expf(-v));
      oo[j]=v;
    }
    *(float4*)(C + (size_t)(m0+ty*4+i)*512 + n0 + tx*4) = o;
  }
}

// out = h + A@h
__global__ void k_spmm_add(const float* __restrict__ h, const u32* __restrict__ bm, float* __restrict__ out){
  int node = blockIdx.x*4 + (threadIdx.x>>6);
  int lane = threadIdx.x & 63;
  int base = node & ~255;
  float acc[8];
  #pragma unroll
  for(int k=0;k<8;++k) acc[k] = h[(size_t)node*DD + lane + 64*k];
  #pragma unroll
  for(int w=0;w<NWORDS;++w){
    u32 m = bm[node*NWORDS+w]; int b0=w<<5;
    while(m){ int j=__ffs((int)m)-1; m&=m-1;
      const float* hr = h + (size_t)(base+b0+j)*DD;
      #pragma unroll
      for(int k=0;k<8;++k) acc[k] += hr[lane+64*k];
    }
  }
  #pragma unroll
  for(int k=0;k<8;++k) out[(size_t)node*DD + lane + 64*k] = acc[k];
}

// prob = sigmoid(sigmoid(h@w33 + b33))
__global__ void k_gemv_prob(const float* __restrict__ h, const float* __restrict__ w33,
                            const float* __restrict__ b33, float* __restrict__ prob){
  int node = blockIdx.x*4 + (threadIdx.x>>6);
  int lane = threadIdx.x & 63;
  float acc = 0.0f;
  #pragma unroll
  for(int k=0;k<8;++k) acc = fmaf(h[(size_t)node*512 + lane + 64*k], w33[lane+64*k], acc);
  #pragma unroll
  for(int off=32;off>0;off>>=1) acc += __shfl_down(acc, off);
  if(lane==0){
    float z = sigmoidf_(acc + b33[0]);
    prob[node] = sigmoidf_(z);
  }
}

// ---------------- y = A@prob (fp64), per-graph c_g and gamma partials ----------------
__global__ __launch_bounds__(256) void k_y(const u32* __restrict__ bm, const float* __restrict__ prob,
                 const float* __restrict__ ent, double* __restrict__ y,
                 double* __restrict__ cg, double* __restrict__ gam){
  __shared__ float p_s[256];
  __shared__ double redc[4], redg[4];
  int g = blockIdx.x, i = threadIdx.x;
  int node = (g<<8) + i;
  float p = prob[node];
  p_s[i] = p;
  __syncthreads();
  double acc = 0.0;
  #pragma unroll
  for (int w = 0; w < NWORDS; ++w){
    u32 m = bm[(size_t)node*NWORDS + w];
    while (m){ int j=__ffs((int)m)-1; m&=m-1; acc += (double)p_s[(w<<5)+j]; }
  }
  y[node] = acc;
  double e = (double)ent[node];
  double c = (double)p*acc - e*(double)p;
  #pragma unroll
  for (int off=32; off>0; off>>=1){ c += __shfl_down(c,off); e += __shfl_down(e,off); }
  if ((i&63)==0){ redc[i>>6]=c; redg[i>>6]=e; }
  __syncthreads();
  if (i==0){ cg[g]=redc[0]+redc[1]+redc[2]+redc[3]; gam[g]=redg[0]+redg[1]+redg[2]+redg[3]; }
}

// ---------------- bitonic sort: order = argsort(-prob) stable ----------------
__global__ void k_sort(const float* __restrict__ prob, int* __restrict__ order){
  __shared__ float kp[NN];
  __shared__ int ki[NN];
  int tid = threadIdx.x; // 1024
  for(int t=tid;t<NN;t+=1024){ kp[t]=prob[t]; ki[t]=t; }
  __syncthreads();
  for(int k=2;k<=NN;k<<=1){
    for(int j=k>>1;j>0;j>>=1){
      for(int t=tid;t<NN;t+=1024){
        int l = t ^ j;
        if(l > t){
          bool up = ((t & k) == 0);
          float pa=kp[t]; int ia=ki[t]; float pb=kp[l]; int ib=ki[l];
          bool before_ab = (pa > pb) || (pa == pb && ia < ib);
          bool dosw = up ? (!before_ab) : before_ab;
          if(dosw){ kp[t]=pb; ki[t]=ib; kp[l]=pa; ki[l]=ia; }
        }
      }
      __syncthreads();
    }
  }
  for(int t=tid;t<NN;t+=1024) order[t]=ki[t];
}

// ---------------- single-wave incremental greedy scan ----------------
// Eval: e-term over owned columns + pair term via PRECOMPUTED pair lists
// (no divergent dependent bit-walks). Reduce: 2 shfl_xor folds + 16-slot LDS
// tree read by ALL lanes -> thr replicated per-lane, no broadcast.
// Dead-skip: ballot mask cached in register; re-ballot only on takes.
__global__ void __launch_bounds__(64) k_scan(const u32* __restrict__ bmT, const u32* __restrict__ dead0,
    const float* __restrict__ ent, const float* __restrict__ prob, const int* __restrict__ order,
    const double* __restrict__ yg, const double* __restrict__ cgp, const double* __restrict__ gamp,
    const u16* __restrict__ pairT, const u32* __restrict__ cntT,
    float* __restrict__ selw, float* __restrict__ out_sel, float* __restrict__ out_loss)
{
  extern __shared__ char smem[];
  u32* bmT_s     = (u32*)smem;                    // 64 KB  [8][2048]
  double* y_s    = (double*)(smem + 65536);       // 16 KB
  float* dummy_s = (float*)(smem + 81920);        // 8 KB
  float* entf_s  = (float*)(smem + 90112);        // 8 KB
  int* order_s   = (int*)(smem + 98304);          // 8 KB
  u32* dead_s    = (u32*)(smem + 106496);         // 256 B
  u32* sel_s     = (u32*)(smem + 106752);         // 256 B
  double* red_d  = (double*)(smem + 107008);      // 128 B
  int lane = threadIdx.x;

  for (int t=lane; t<4096; t+=64) ((uint4*)bmT_s)[t] = ((const uint4*)bmT)[t];
  for (int t=lane; t<NN; t+=64){
    dummy_s[t]=prob[t]; entf_s[t]=ent[t]; y_s[t]=yg[t]; order_s[t]=order[t];
  }
  { u32 d0=dead0[lane]; dead_s[lane]=d0; sel_s[lane]=d0; }
  double thr = 0.0;  // replicated on every lane; updated identically
  if (lane==0){
    double gg=0.0, cc=0.0;
    for(int i=0;i<8;++i){ gg+=gamp[i]; cc+=cgp[i]; }
    out_loss[0]=(float)(gg+cc);
  }
  __syncthreads();

  for (int pos=0; pos<NN; pos+=64){
    int myNode = order_s[pos+lane];
    int myW = myNode>>5, myB = myNode&31;
    ull msk;
    { bool aliveMe = !((dead_s[myW]>>myB)&1u); msk = __ballot(aliveMe); }
    while (msk){
      int k = (int)__builtin_ctzll(msk);
      int node = __shfl(myNode, k);        // wave-uniform
      int base = node & ~255, r = node & 255, g = node>>8;

      // prefetch pair list (global, L2/L3-hot)
      int cntp = (int)cntT[node];
      const u16* prow = pairT + (size_t)node*KPAIR;
      u32 pr0 = (lane < cntp)    ? (u32)prow[lane]    : 0u;
      u32 pr1 = (lane+64 < cntp) ? (u32)prow[lane+64] : 0u;

      u32 rv[8];
      #pragma unroll
      for(int w=0;w<8;++w) rv[w]=bmT_s[(w<<11)+node];  // broadcast
      float uv = 1.0f - dummy_s[node];                 // broadcast

      double part = 0.0;
      #pragma unroll
      for(int q=0;q<4;++q){
        int cl = lane + (q<<6);
        int c  = base + cl;
        bool isnb   = (rv[cl>>5]>>(cl&31))&1u;
        bool isself = (cl==r);
        if (isnb | isself){
          float  d  = dummy_s[c];
          double yv = y_s[c];
          float  e  = entf_s[c];
          float  u  = isself ? uv : -d;
          part += (double)u*(2.0*yv-(double)e);
          if (isnb) part -= 2.0*(double)uv*(double)d;
        }
      }
      // pair term: 2 * sum over intra-neighborhood edges (i<l) of d_i*d_l
      if (lane < cntp){
        float di = dummy_s[base + (int)(pr0>>8)];
        float dl = dummy_s[base + (int)(pr0&255u)];
        part += 2.0*(double)di*(double)dl;
      }
      if (lane+64 < cntp){
        float di = dummy_s[base + (int)(pr1>>8)];
        float dl = dummy_s[base + (int)(pr1&255u)];
        part += 2.0*(double)di*(double)dl;
      }

      // fold to 16 groups, then shared tree read by all lanes (uniform result)
      part += __shfl_xor(part, 32);
      part += __shfl_xor(part, 16);
      if (lane < 16) red_d[lane] = part;
      __syncthreads();
      double s0 = (red_d[0]+red_d[1]) + (red_d[2]+red_d[3]);
      double s1 = (red_d[4]+red_d[5]) + (red_d[6]+red_d[7]);
      double s2 = (red_d[8]+red_d[9]) + (red_d[10]+red_d[11]);
      double s3 = (red_d[12]+red_d[13]) + (red_d[14]+red_d[15]);
      double tot = (s0+s1)+(s2+s3);

      if (tot <= thr){
        thr -= tot;
        u32 supp[8];
        #pragma unroll
        for(int w=0;w<8;++w) supp[w]=rv[w];
        supp[r>>5] |= 1u<<(r&31);
        if (lane<8) dead_s[(g<<3)+lane] |= supp[lane];
        if (lane==0) sel_s[node>>5] |= 1u<<(node&31);
        // y update FIRST, reading OLD dummy values from LDS
        #pragma unroll
        for(int q=0;q<4;++q){
          int cl=lane+(q<<6); int c=base+cl;
          double dy=0.0;
          #pragma unroll
          for(int w=0;w<8;++w){
            u32 m = bmT_s[(w<<11)+c] & supp[w];
            while(m){
              int j=__ffs((int)m)-1; m&=m-1;
              int j2=(w<<5)+j;
              float ujf = (j2==r) ? uv : -dummy_s[base+j2];
              dy += (double)ujf;
            }
          }
          if (dy!=0.0) y_s[c]+=dy;
        }
        __syncthreads();   // all old-dummy reads complete before overwrite
        #pragma unroll
        for(int q=0;q<4;++q){
          int cl=lane+(q<<6); int c=base+cl;
          bool isnb = (rv[cl>>5]>>(cl&31))&1u;
          if (cl==r) dummy_s[c]=1.0f;
          else if (isnb) dummy_s[c]=0.0f;
        }
        __syncthreads();
        // re-filter mask: this take may have killed pending nodes (incl. node k)
        bool aliveMe = ((msk>>lane)&1ull) && !((dead_s[myW]>>myB)&1u);
        msk = __ballot(aliveMe);
      } else {
        msk &= ~(1ull<<k);   // processed, no state change
      }
    }
  }

  for (int t=lane; t<NN; t+=64){
    float sv = ((sel_s[t>>5]>>(t&31))&1u)?1.0f:0.0f;
    selw[t]=sv; out_sel[t]=sv;
  }
}

// ---------------- outputs ----------------
__global__ void k_xpool(const float* __restrict__ x, const float* __restrict__ selw, float* __restrict__ out){
  int t = blockIdx.x*256+threadIdx.x;
  if(t >= NN*(DD/4)) return;
  int i = t >> 7;
  float s = selw[i];
  float4 v = ((const float4*)x)[t];
  v.x*=s; v.y*=s; v.z*=s; v.w*=s;
  ((float4*)out)[t] = v;
}

__global__ void k_adj(const u32* __restrict__ bm, const u32* __restrict__ bm2,
                      const float* __restrict__ selw, float* __restrict__ outadj){
  int r = blockIdx.x;
  int c = blockIdx.y*256 + threadIdx.x;
  float val = 0.0f;
  if ((r>>8)==(c>>8) && r!=c && selw[r]!=0.0f && selw[c]!=0.0f){
    int lc = c & 255;
    u32 any = (bm2[r*NWORDS + (lc>>5)] >> (lc&31)) & 1u;
    if(!any){
      #pragma unroll
      for(int w=0;w<NWORDS;++w) any |= (bm2[r*NWORDS+w] & bm[c*NWORDS+w]);
    }
    val = any ? 1.0f : 0.0f;
  }
  outadj[(size_t)r*2048 + c] = val;
}

extern "C" void kernel_launch(void* const* d_in, const int* in_sizes, int n_in,
                              void* d_out, int out_size, void* d_ws, size_t ws_size,
                              hipStream_t stream){
  const float* x  = (const float*)d_in[0];
  const int* ei   = (const int*)d_in[1];
  const float* w11=(const float*)d_in[3];  const float* b11=(const float*)d_in[4];
  const float* w12=(const float*)d_in[5];  const float* b12=(const float*)d_in[6];
  const float* w13=(const float*)d_in[7];  const float* b13=(const float*)d_in[8];
  const float* w21=(const float*)d_in[9];  const float* b21=(const float*)d_in[10];
  const float* w22=(const float*)d_in[11]; const float* b22=(const float*)d_in[12];
  const float* w23=(const float*)d_in[13]; const float* b23=(const float*)d_in[14];
  const float* w31=(const float*)d_in[15]; const float* b31=(const float*)d_in[16];
  const float* w32=(const float*)d_in[17]; const float* b32=(const float*)d_in[18];
  const float* w33=(const float*)d_in[19]; const float* b33=(const float*)d_in[20];

  char* ws = (char*)d_ws;
  u32* bm    = (u32*)(ws + 0);
  u32* bm2   = (u32*)(ws + 65536);
  int* deg   = (int*)(ws + 131072);
  float* Vn  = (float*)(ws + 139264);
  float* ent = (float*)(ws + 147456);
  float* uarr= (float*)(ws + 155648);
  float* prob= (float*)(ws + 163840);
  int* order = (int*)(ws + 172032);
  float* selw= (float*)(ws + 180224);
  double* yg = (double*)(ws + 196608);
  double* cg = (double*)(ws + 212992);
  double* gam= (double*)(ws + 213056);
  u32* bmT   = (u32*)(ws + 215040);    // 64 KB transposed bitmask
  u32* dead0 = (u32*)(ws + 313344);    // 256 B
  u16* pairT = (u16*)(ws + 327680);    // 2048*128*2 = 512 KB
  u32* cntT  = (u32*)(ws + 851968);    // 8 KB
  float* buf0= (float*)(ws + (1<<20));
  float* buf1= (float*)(ws + (1<<20) + (size_t)NN*DD*4);

  float* out = (float*)d_out;
  float* out_xp   = out;
  float* out_adj  = out + 1048576;
  float* out_sel  = out + 1048576 + 4194304;
  float* out_loss = out + 1048576 + 4194304 + 2048;

  hipFuncSetAttribute((const void*)k_scan, hipFuncAttributeMaxDynamicSharedMemorySize, 107136);

  k_zero_bm<<<65,256,0,stream>>>(bm, dead0);
  k_scatter<<<128,256,0,stream>>>(ei, bm);
  k_bm2_deg<<<8,256,0,stream>>>(bm, bm2, deg, bmT, dead0, pairT, cntT);
  k_vn<<<512,256,0,stream>>>(x, bm, deg, Vn);
  k_softent<<<8,256,0,stream>>>(Vn, ent);
  k_u<<<8,256,0,stream>>>(bm, ent, uarr);
  k_h1<<<4096,256,0,stream>>>(uarr, w11, b11, buf0);
  dim3 gg(32,8);
  k_gemm<0><<<gg,256,0,stream>>>(buf0, w12, b12, buf1);
  k_gemm<1><<<gg,256,0,stream>>>(buf1, w13, b13, buf0);
  k_spmm_add<<<512,256,0,stream>>>(buf0, bm, buf1);
  k_gemm<0><<<gg,256,0,stream>>>(buf1, w21, b21, buf0);
  k_gemm<0><<<gg,256,0,stream>>>(buf0, w22, b22, buf1);
  k_gemm<1><<<gg,256,0,stream>>>(buf1, w23, b23, buf0);
  k_spmm_add<<<512,256,0,stream>>>(buf0, bm, buf1);
  k_gemm<0><<<gg,256,0,stream>>>(buf1, w31, b31, buf0);
  k_gemm<0><<<gg,256,0,stream>>>(buf0, w32, b32, buf1);
  k_gemv_prob<<<512,256,0,stream>>>(buf1, w33, b33, prob);
  k_y<<<8,256,0,stream>>>(bm, prob, ent, yg, cg, gam);
  k_sort<<<1,1024,0,stream>>>(prob, order);
  k_scan<<<1,64,107136,stream>>>(bmT, dead0, ent, prob, order, yg, cg, gam, pairT, cntT, selw, out_sel, out_loss);
  k_xpool<<<1024,256,0,stream>>>(x, selw, out_xp);
  dim3 ga(2048,8);
  k_adj<<<ga,256,0,stream>>>(bm, bm2, selw, out_adj);
}